// Round 9
// baseline (265.698 us; speedup 1.0000x reference)
//
#include <hip/hip_runtime.h>
#include <hip/hip_bf16.h>

#define B_ 8
#define D_ 64
#define N_ 4096
#define M_ 4096
#define B3N (B_*3*N_)

// exp(s/8) = exp2(s * 0.125 * log2(e)) ; SCALE2 folded into Q prepass
#define SCALE2 0.18033688011112042f

typedef short bf16x8 __attribute__((ext_vector_type(8)));
typedef float f32x4 __attribute__((ext_vector_type(4)));
typedef __fp16 half2v __attribute__((ext_vector_type(2)));
typedef __fp16 half4v __attribute__((ext_vector_type(4)));
typedef unsigned int uint4v __attribute__((ext_vector_type(4)));

#if __has_builtin(__builtin_amdgcn_exp2f)
#define EXP2(x) __builtin_amdgcn_exp2f(x)
#else
#define EXP2(x) exp2f(x)
#endif

__device__ __forceinline__ unsigned fbits(float f) { return __builtin_bit_cast(unsigned, f); }

// pack two f32 -> one u32 of two bf16 (truncation) : [lo16]=lo, [hi16]=hi
__device__ __forceinline__ unsigned pkbf(float hi, float lo) {
#if __has_builtin(__builtin_amdgcn_perm)
    return __builtin_amdgcn_perm(fbits(hi), fbits(lo), 0x07060302u);
#else
    return (fbits(hi) & 0xFFFF0000u) | (fbits(lo) >> 16);
#endif
}

__device__ __forceinline__ half2v pkhalf(float a, float b) {
#if __has_builtin(__builtin_amdgcn_cvt_pkrtz)
    return __builtin_bit_cast(half2v, __builtin_amdgcn_cvt_pkrtz(a, b));   // low=a, high=b
#else
    half2v r; r[0] = (__fp16)a; r[1] = (__fp16)b; return r;
#endif
}

// legacy-shape MFMA builtin (V4h x V4h -> V4f), verified compiles+correct r5.
#define MFMA_PV(a,b,c) __builtin_amdgcn_mfma_f32_16x16x16f16((a),(b),(c),0,0,0)

// ---- prepass 1: [b][d][p] f32 -> [b][p][d] bf16 (trunc), scale folded into Q
__global__ __launch_bounds__(64) void prep_kernel(const float* __restrict__ qe,
                                                  const float* __restrict__ ke,
                                                  unsigned short* __restrict__ qb,
                                                  unsigned short* __restrict__ kb)
{
    int blk = blockIdx.x;            // 0..1023 ; >=512 -> Q with scale
    bool isq = blk >= 512;
    int l  = blk & 511;
    int b  = l >> 6;
    int p  = ((l & 63) << 6) + threadIdx.x;
    const float* ip = (isq ? qe : ke) + (size_t)b * D_ * M_ + p;
    unsigned short* op = (isq ? qb : kb) + ((size_t)b * M_ + p) * D_;
    float sc = isq ? SCALE2 : 1.0f;
    #pragma unroll
    for (int i = 0; i < 8; ++i) {
        float v[8];
        #pragma unroll
        for (int d = 0; d < 8; ++d) v[d] = ip[(size_t)(8*i + d) * M_] * sc;
        uint4v w;
        #pragma unroll
        for (int j = 0; j < 4; ++j) w[j] = pkbf(v[2*j+1], v[2*j]);
        *(uint4v*)(op + 8*i) = w;
    }
}

// ---- prepass 2: src copy-through + tgt -> fp16 table [b][4][M] = {x,y,z,1}
__global__ __launch_bounds__(256) void prep2_kernel(const float4* __restrict__ src4,
                                                    const float* __restrict__ tgt,
                                                    float4* __restrict__ out4,
                                                    __fp16* __restrict__ th)
{
    int i = blockIdx.x * 256 + threadIdx.x;
    if (blockIdx.x < 96) {                 // 96*256 = 24576 = B*3*N/4
        out4[i] = src4[i];
    } else {
        int j = i - 96*256;                // 0..B*M-1
        int b = j >> 12, m = j & (M_-1);
        const float* tp = tgt + ((size_t)b*3)*M_ + m;
        __fp16* op = th + ((size_t)b*4)*M_ + m;
        op[0]      = (__fp16)tp[0];
        op[M_]     = (__fp16)tp[(size_t)M_];
        op[2*M_]   = (__fp16)tp[(size_t)2*M_];
        op[3*M_]   = (__fp16)1.0f;
    }
}

// ---- main attention kernel: 4 waves = 4 m-slices, full-occupancy -----------
// grid (N/64, 4, B), block 256. Wave w: slice = by*4+w (S=16), n-tile = bx*64.
// Waves share Q rows (L1) but stream DIFFERENT K chunks (decorrelated loads).
// QK^T: mfma_f32_16x16x32_bf16(K,Q); c4: row m_local=4g+r, col n=lm (verified).
// PV+denom: mfma 16x16x16 f16, A rows = {x,y,z,1} repeated 4x -> result
// replicated across g-groups; epilogue: group g writes partials row (g+3)&3.
__global__ __launch_bounds__(256, 8)
void attn5_kernel(const unsigned short* __restrict__ qb,
                  const unsigned short* __restrict__ kb,
                  const __fp16* __restrict__ th,
                  float* __restrict__ partials)
{
    const int lane = threadIdx.x & 63;
    const int wave = threadIdx.x >> 6;
    const int lm = lane & 15, g = lane >> 4;
    const int b = blockIdx.z;
    const int slice = blockIdx.y * 4 + wave;      // 0..15
    const int n0 = blockIdx.x * 64;
    const int mchunk = M_ / 16, mbase = slice * mchunk;   // 256 rows/wave

    // Q fragments (B-operand): lane holds col n=n0+16f+lm, k=32h+8g+jj
    bf16x8 qf[4][2];
    #pragma unroll
    for (int f = 0; f < 4; ++f) {
        const unsigned short* qrow = qb + ((size_t)b * N_ + n0 + 16*f + lm) * D_ + 8*g;
        qf[f][0] = *(const bf16x8*)(qrow);
        qf[f][1] = *(const bf16x8*)(qrow + 32);
    }

    const unsigned short* krow = kb + ((size_t)b * M_ + mbase + lm) * D_ + 8*g;
    const __fp16* tp = th + ((size_t)b * 4 + (lm & 3)) * M_ + mbase + 4*g;

    f32x4 D2a[4] = {{0,0,0,0},{0,0,0,0},{0,0,0,0},{0,0,0,0}};
    f32x4 D2b[4] = {{0,0,0,0},{0,0,0,0},{0,0,0,0},{0,0,0,0}};

    auto compute = [&](bf16x8 kA, bf16x8 kB, half4v aF, f32x4* Dacc) {
        #pragma unroll
        for (int f = 0; f < 4; ++f) {
            f32x4 c4 = {0,0,0,0};
            c4 = __builtin_amdgcn_mfma_f32_16x16x32_bf16(kA, qf[f][0], c4, 0, 0, 0);
            c4 = __builtin_amdgcn_mfma_f32_16x16x32_bf16(kB, qf[f][1], c4, 0, 0, 0);
            float e0 = EXP2(c4[0]);
            float e1 = EXP2(c4[1]);
            float e2 = EXP2(c4[2]);
            float e3 = EXP2(c4[3]);
            half2v p01 = pkhalf(e0, e1);
            half2v p23 = pkhalf(e2, e3);
            half4v pbf = __builtin_shufflevector(p01, p23, 0, 1, 2, 3);
            Dacc[f] = MFMA_PV(aF, pbf, Dacc[f]);
        }
    };

    // stream 0: rows +0..15 ; stream 1: rows +16..31 (independent acc chains)
    bf16x8 ka0 = *(const bf16x8*)(krow);
    bf16x8 kb0 = *(const bf16x8*)(krow + 32);
    bf16x8 ka1 = *(const bf16x8*)(krow + 16*D_);
    bf16x8 kb1 = *(const bf16x8*)(krow + 16*D_ + 32);
    half4v af0 = *(const half4v*)(tp);
    half4v af1 = *(const half4v*)(tp + 16);

    const int iters = mchunk / 32;   // 8
    for (int it = 0; it < iters - 1; ++it) {
        bf16x8 ka0n = *(const bf16x8*)(krow + 32*D_);
        bf16x8 kb0n = *(const bf16x8*)(krow + 32*D_ + 32);
        bf16x8 ka1n = *(const bf16x8*)(krow + 48*D_);
        bf16x8 kb1n = *(const bf16x8*)(krow + 48*D_ + 32);
        half4v af0n = *(const half4v*)(tp + 32);
        half4v af1n = *(const half4v*)(tp + 48);
        compute(ka0, kb0, af0, D2a);
        compute(ka1, kb1, af1, D2b);
        ka0 = ka0n; kb0 = kb0n; ka1 = ka1n; kb1 = kb1n; af0 = af0n; af1 = af1n;
        krow += 32*D_; tp += 32;
    }
    compute(ka0, kb0, af0, D2a);
    compute(ka1, kb1, af1, D2b);

    #pragma unroll
    for (int f = 0; f < 4; ++f) D2a[f] += D2b[f];

    // result replicated across g-groups: group g writes partials row g.
    // row0=denom=D[3], row1=x=D[0], row2=y=D[1], row3=z=D[2]  -> D[(g+3)&3]
    {
        size_t base = ((size_t)slice * B_ + b) * 4 * N_ + (size_t)g * N_;
        const int sel = (g + 3) & 3;
        #pragma unroll
        for (int f = 0; f < 4; ++f)
            partials[base + n0 + 16*f + lm] = D2a[f][sel];
    }
}

// ---- 1-wave fallback (round-5 passing kernel) ------------------------------
template<int S>
__global__ __launch_bounds__(64, 4)
void attn2_kernel(const unsigned short* __restrict__ qb,
                  const unsigned short* __restrict__ kb,
                  const float* __restrict__ tgt,
                  float* __restrict__ partials)
{
    const int t  = threadIdx.x, lm = t & 15, g = t >> 4;
    const int b  = blockIdx.z, slice = blockIdx.y, n0 = blockIdx.x * 64;
    const int mchunk = M_ / S, mbase = slice * mchunk;

    bf16x8 qf[4][2];
    #pragma unroll
    for (int f = 0; f < 4; ++f) {
        const unsigned short* qrow = qb + ((size_t)b * N_ + n0 + 16*f + lm) * D_ + 8*g;
        qf[f][0] = *(const bf16x8*)(qrow);
        qf[f][1] = *(const bf16x8*)(qrow + 32);
    }

    const bool isones = (lm & 3) == 3;
    const int  c_ld   = isones ? 2 : (lm & 3);
    half2v one2 = pkhalf(1.0f, 1.0f);
    const half4v ones4 = __builtin_shufflevector(one2, one2, 0, 1, 0, 1);

    const unsigned short* krow = kb + ((size_t)b * M_ + mbase + lm) * D_ + 8*g;
    const float* tp = tgt + ((size_t)b * 3 + c_ld) * M_ + mbase + 4*g;

    f32x4 D2[4] = {{0,0,0,0},{0,0,0,0},{0,0,0,0},{0,0,0,0}};

    for (int ms = 0; ms < mchunk; ms += 16) {
        bf16x8 ka  = *(const bf16x8*)(krow);
        bf16x8 kb8 = *(const bf16x8*)(krow + 32);
        f32x4 tv = *(const f32x4*)(tp);
        half2v a01 = pkhalf(tv[0], tv[1]);
        half2v a23 = pkhalf(tv[2], tv[3]);
        half4v afr = __builtin_shufflevector(a01, a23, 0, 1, 2, 3);
        afr = isones ? ones4 : afr;

        #pragma unroll
        for (int f = 0; f < 4; ++f) {
            f32x4 c4 = {0,0,0,0};
            c4 = __builtin_amdgcn_mfma_f32_16x16x32_bf16(ka,  qf[f][0], c4, 0, 0, 0);
            c4 = __builtin_amdgcn_mfma_f32_16x16x32_bf16(kb8, qf[f][1], c4, 0, 0, 0);
            float e0 = EXP2(c4[0]);
            float e1 = EXP2(c4[1]);
            float e2 = EXP2(c4[2]);
            float e3 = EXP2(c4[3]);
            half2v p01 = pkhalf(e0, e1);
            half2v p23 = pkhalf(e2, e3);
            half4v pbf = __builtin_shufflevector(p01, p23, 0, 1, 2, 3);
            D2[f] = MFMA_PV(afr, pbf, D2[f]);
        }
        krow += 16 * D_;
        tp   += 16;
    }

    if (t < 16) {
        size_t base = ((size_t)slice * B_ + b) * 4 * N_;
        #pragma unroll
        for (int f = 0; f < 4; ++f) {
            int n = n0 + 16*f + t;
            partials[base + 0*N_ + n] = D2[f][3];
            partials[base + 1*N_ + n] = D2[f][0];
            partials[base + 2*N_ + n] = D2[f][1];
            partials[base + 3*N_ + n] = D2[f][2];
        }
    }
}

// ---- epilogue kernels -------------------------------------------------------
__global__ void copy_kernel(const float4* __restrict__ src, float4* __restrict__ out) {
    int i = blockIdx.x*256 + threadIdx.x;
    out[i] = src[i];
}

template<int S>
__global__ void finalize_kernel(const float* __restrict__ ws, float* __restrict__ out) {
    int tid = blockIdx.x*256 + threadIdx.x;  // B*N threads
    int b = tid >> 12;
    int n = tid & (N_-1);
    float den = 0.f, x = 0.f, y = 0.f, z = 0.f;
    #pragma unroll
    for (int s = 0; s < S; ++s) {
        size_t base = ((size_t)s*B_ + b)*4*N_ + n;
        den += ws[base];
        x   += ws[base + 1*N_];
        y   += ws[base + 2*N_];
        z   += ws[base + 3*N_];
    }
    float inv = 1.0f/den;
    out[B3N + ((size_t)b*3 + 0)*N_ + n] = x*inv;
    out[B3N + ((size_t)b*3 + 1)*N_ + n] = y*inv;
    out[B3N + ((size_t)b*3 + 2)*N_ + n] = z*inv;
}

extern "C" void kernel_launch(void* const* d_in, const int* in_sizes, int n_in,
                              void* d_out, int out_size, void* d_ws, size_t ws_size,
                              hipStream_t stream) {
    const float* qe  = (const float*)d_in[0];   // src_embedding [B,D,N]
    const float* ke  = (const float*)d_in[1];   // tgt_embedding [B,D,M]
    const float* src = (const float*)d_in[2];   // src [B,3,N]
    const float* tg  = (const float*)d_in[3];   // tgt [B,3,M]
    float* out = (float*)d_out;

    const size_t embElems = (size_t)B_ * M_ * D_;             // 2M elems (4MB bf16)
    const size_t embBytes = 2 * embElems * 2;                 // 8 MB (qb+kb)
    const size_t thBytes  = (size_t)B_ * 4 * M_ * 2;          // 256 KB
    const size_t need16   = embBytes + thBytes + (size_t)16 * B_ * 4 * N_ * 4; // ~16.25 MB
    const size_t needOld  = embBytes + (size_t)8 * B_ * 4 * N_ * 4;            // ~12.4 MB

    unsigned short* kb16 = (unsigned short*)d_ws;
    unsigned short* qb16 = kb16 + embElems;
    __fp16* th = (__fp16*)((char*)d_ws + embBytes);
    float* partialsNew = (float*)((char*)d_ws + embBytes + thBytes);
    float* partialsOld = (float*)((char*)d_ws + embBytes);

    if (ws_size >= need16) {
        prep2_kernel<<<224, 256, 0, stream>>>((const float4*)src, tg, (float4*)out, th);
        prep_kernel<<<1024, 64, 0, stream>>>(qe, ke, qb16, kb16);
        dim3 grid(N_/64, 4, B_);   // 2048 blocks x 4 waves = 32 waves/CU (HW cap)
        attn5_kernel<<<grid, 256, 0, stream>>>(qb16, kb16, th, partialsNew);
        finalize_kernel<16><<<(B_*N_)/256, 256, 0, stream>>>(partialsNew, out);
    } else if (ws_size >= needOld) {
        copy_kernel<<<96, 256, 0, stream>>>((const float4*)src, (float4*)out);
        prep_kernel<<<1024, 64, 0, stream>>>(qe, ke, qb16, kb16);
        dim3 grid(N_/64, 8, B_);
        attn2_kernel<8><<<grid, 64, 0, stream>>>(qb16, kb16, tg, partialsOld);
        finalize_kernel<8><<<(B_*N_)/256, 256, 0, stream>>>(partialsOld, out);
    }
}

// Round 10
// 108.294 us; speedup vs baseline: 2.4535x; 2.4535x over previous
//
#include <hip/hip_runtime.h>
#include <hip/hip_bf16.h>

#define B_ 8
#define D_ 64
#define N_ 4096
#define M_ 4096
#define B3N (B_*3*N_)

// exp(s/8) = exp2(s * 0.125 * log2(e)) ; SCALE2 folded into Q prepass
#define SCALE2 0.18033688011112042f

typedef short bf16x8 __attribute__((ext_vector_type(8)));
typedef float f32x4 __attribute__((ext_vector_type(4)));
typedef __fp16 half2v __attribute__((ext_vector_type(2)));
typedef __fp16 half4v __attribute__((ext_vector_type(4)));
typedef unsigned int uint4v __attribute__((ext_vector_type(4)));

#if __has_builtin(__builtin_amdgcn_exp2f)
#define EXP2(x) __builtin_amdgcn_exp2f(x)
#else
#define EXP2(x) exp2f(x)
#endif

__device__ __forceinline__ unsigned fbits(float f) { return __builtin_bit_cast(unsigned, f); }

__device__ __forceinline__ unsigned pkbf(float hi, float lo) {
#if __has_builtin(__builtin_amdgcn_perm)
    return __builtin_amdgcn_perm(fbits(hi), fbits(lo), 0x07060302u);
#else
    return (fbits(hi) & 0xFFFF0000u) | (fbits(lo) >> 16);
#endif
}

__device__ __forceinline__ half2v pkhalf(float a, float b) {
#if __has_builtin(__builtin_amdgcn_cvt_pkrtz)
    return __builtin_bit_cast(half2v, __builtin_amdgcn_cvt_pkrtz(a, b));   // low=a, high=b
#else
    half2v r; r[0] = (__fp16)a; r[1] = (__fp16)b; return r;
#endif
}

// legacy-shape MFMA builtin (V4h x V4h -> V4f), verified compiles+correct r5.
#define MFMA_PV(a,b,c) __builtin_amdgcn_mfma_f32_16x16x16f16((a),(b),(c),0,0,0)

// ---- prepass 1: [b][d][p] f32 -> [b][p][d] bf16 (trunc), scale folded into Q
__global__ __launch_bounds__(64) void prep_kernel(const float* __restrict__ qe,
                                                  const float* __restrict__ ke,
                                                  unsigned short* __restrict__ qb,
                                                  unsigned short* __restrict__ kb)
{
    int blk = blockIdx.x;            // 0..1023 ; >=512 -> Q with scale
    bool isq = blk >= 512;
    int l  = blk & 511;
    int b  = l >> 6;
    int p  = ((l & 63) << 6) + threadIdx.x;
    const float* ip = (isq ? qe : ke) + (size_t)b * D_ * M_ + p;
    unsigned short* op = (isq ? qb : kb) + ((size_t)b * M_ + p) * D_;
    float sc = isq ? SCALE2 : 1.0f;
    #pragma unroll
    for (int i = 0; i < 8; ++i) {
        float v[8];
        #pragma unroll
        for (int d = 0; d < 8; ++d) v[d] = ip[(size_t)(8*i + d) * M_] * sc;
        uint4v w;
        #pragma unroll
        for (int j = 0; j < 4; ++j) w[j] = pkbf(v[2*j+1], v[2*j]);
        *(uint4v*)(op + 8*i) = w;
    }
}

// ---- prepass 2: src copy-through + tgt -> fp16 table [b][4][M] = {x,y,z,1}
__global__ __launch_bounds__(256) void prep2_kernel(const float4* __restrict__ src4,
                                                    const float* __restrict__ tgt,
                                                    float4* __restrict__ out4,
                                                    __fp16* __restrict__ th)
{
    int i = blockIdx.x * 256 + threadIdx.x;
    if (blockIdx.x < 96) {                 // 96*256 = 24576 = B*3*N/4
        out4[i] = src4[i];
    } else {
        int j = i - 96*256;                // 0..B*M-1
        int b = j >> 12, m = j & (M_-1);
        const float* tp = tgt + ((size_t)b*3)*M_ + m;
        __fp16* op = th + ((size_t)b*4)*M_ + m;
        op[0]      = (__fp16)tp[0];
        op[M_]     = (__fp16)tp[(size_t)M_];
        op[2*M_]   = (__fp16)tp[(size_t)2*M_];
        op[3*M_]   = (__fp16)1.0f;
    }
}

// ---- attn6: register-dieted high-TLP variant (A-half of the A/B) -----------
// n-tile 32/wave, single m-stream, no manual prefetch. Target <=56 VGPR so the
// 8-waves/SIMD (32 waves/CU) tier is reachable WITHOUT spill.
// Wave w: slice = SOFF + blockIdx.y*4 + w ; 256 m-rows per wave.
template<int SOFF>
__global__ __launch_bounds__(256, 8)
void attn6_kernel(const unsigned short* __restrict__ qb,
                  const unsigned short* __restrict__ kb,
                  const __fp16* __restrict__ th,
                  float* __restrict__ partials)
{
    const int lane = threadIdx.x & 63;
    const int wave = threadIdx.x >> 6;
    const int lm = lane & 15, g = lane >> 4;
    const int b = blockIdx.z;
    const int slice = SOFF + blockIdx.y * 4 + wave;
    const int n0 = blockIdx.x * 32;
    const int mchunk = M_ / 16, mbase = slice * mchunk;   // 256 rows/wave

    // Q fragments (B-operand): lane holds col n=n0+16f+lm, k=32h+8g+jj
    bf16x8 qf[2][2];
    #pragma unroll
    for (int f = 0; f < 2; ++f) {
        const unsigned short* qrow = qb + ((size_t)b * N_ + n0 + 16*f + lm) * D_ + 8*g;
        qf[f][0] = *(const bf16x8*)(qrow);
        qf[f][1] = *(const bf16x8*)(qrow + 32);
    }

    const unsigned short* krow = kb + ((size_t)b * M_ + mbase + lm) * D_ + 8*g;
    const __fp16* tp = th + ((size_t)b * 4 + (lm & 3)) * M_ + mbase + 4*g;

    f32x4 D2[2] = {{0,0,0,0},{0,0,0,0}};

    for (int ms = 0; ms < mchunk; ms += 16) {
        bf16x8 ka  = *(const bf16x8*)(krow);
        bf16x8 kb8 = *(const bf16x8*)(krow + 32);
        half4v af  = *(const half4v*)(tp);
        #pragma unroll
        for (int f = 0; f < 2; ++f) {
            f32x4 c4 = {0,0,0,0};
            c4 = __builtin_amdgcn_mfma_f32_16x16x32_bf16(ka,  qf[f][0], c4, 0, 0, 0);
            c4 = __builtin_amdgcn_mfma_f32_16x16x32_bf16(kb8, qf[f][1], c4, 0, 0, 0);
            float e0 = EXP2(c4[0]);
            float e1 = EXP2(c4[1]);
            float e2 = EXP2(c4[2]);
            float e3 = EXP2(c4[3]);
            half2v p01 = pkhalf(e0, e1);
            half2v p23 = pkhalf(e2, e3);
            half4v pbf = __builtin_shufflevector(p01, p23, 0, 1, 2, 3);
            D2[f] = MFMA_PV(af, pbf, D2[f]);
        }
        krow += 16 * D_;
        tp   += 16;
    }

    // result replicated across g-groups: group g writes partials row g.
    // row0=denom=D[3], row1=x=D[0], row2=y=D[1], row3=z=D[2]  -> D[(g+3)&3]
    {
        size_t base = ((size_t)slice * B_ + b) * 4 * N_ + (size_t)g * N_;
        const int sel = (g + 3) & 3;
        #pragma unroll
        for (int f = 0; f < 2; ++f)
            partials[base + n0 + 16*f + lm] = D2[f][sel];
    }
}

// ---- attn5b: attn4 body (f=4, ILP-2), safe (256,4) regalloc (B-half) -------
template<int SOFF>
__global__ __launch_bounds__(256, 4)
void attn5b_kernel(const unsigned short* __restrict__ qb,
                   const unsigned short* __restrict__ kb,
                   const __fp16* __restrict__ th,
                   float* __restrict__ partials)
{
    const int lane = threadIdx.x & 63;
    const int wave = threadIdx.x >> 6;
    const int lm = lane & 15, g = lane >> 4;
    const int b = blockIdx.z;
    const int slice = SOFF + blockIdx.y * 4 + wave;
    const int n0 = blockIdx.x * 64;
    const int mchunk = M_ / 16, mbase = slice * mchunk;   // 256 rows/wave

    bf16x8 qf[4][2];
    #pragma unroll
    for (int f = 0; f < 4; ++f) {
        const unsigned short* qrow = qb + ((size_t)b * N_ + n0 + 16*f + lm) * D_ + 8*g;
        qf[f][0] = *(const bf16x8*)(qrow);
        qf[f][1] = *(const bf16x8*)(qrow + 32);
    }

    const unsigned short* krow = kb + ((size_t)b * M_ + mbase + lm) * D_ + 8*g;
    const __fp16* tp = th + ((size_t)b * 4 + (lm & 3)) * M_ + mbase + 4*g;

    f32x4 D2a[4] = {{0,0,0,0},{0,0,0,0},{0,0,0,0},{0,0,0,0}};
    f32x4 D2b[4] = {{0,0,0,0},{0,0,0,0},{0,0,0,0},{0,0,0,0}};

    auto compute = [&](bf16x8 kA, bf16x8 kB, half4v aF, f32x4* Dacc) {
        #pragma unroll
        for (int f = 0; f < 4; ++f) {
            f32x4 c4 = {0,0,0,0};
            c4 = __builtin_amdgcn_mfma_f32_16x16x32_bf16(kA, qf[f][0], c4, 0, 0, 0);
            c4 = __builtin_amdgcn_mfma_f32_16x16x32_bf16(kB, qf[f][1], c4, 0, 0, 0);
            float e0 = EXP2(c4[0]);
            float e1 = EXP2(c4[1]);
            float e2 = EXP2(c4[2]);
            float e3 = EXP2(c4[3]);
            half2v p01 = pkhalf(e0, e1);
            half2v p23 = pkhalf(e2, e3);
            half4v pbf = __builtin_shufflevector(p01, p23, 0, 1, 2, 3);
            Dacc[f] = MFMA_PV(aF, pbf, Dacc[f]);
        }
    };

    bf16x8 ka0 = *(const bf16x8*)(krow);
    bf16x8 kb0 = *(const bf16x8*)(krow + 32);
    bf16x8 ka1 = *(const bf16x8*)(krow + 16*D_);
    bf16x8 kb1 = *(const bf16x8*)(krow + 16*D_ + 32);
    half4v af0 = *(const half4v*)(tp);
    half4v af1 = *(const half4v*)(tp + 16);

    const int iters = mchunk / 32;   // 8
    for (int it = 0; it < iters - 1; ++it) {
        bf16x8 ka0n = *(const bf16x8*)(krow + 32*D_);
        bf16x8 kb0n = *(const bf16x8*)(krow + 32*D_ + 32);
        bf16x8 ka1n = *(const bf16x8*)(krow + 48*D_);
        bf16x8 kb1n = *(const bf16x8*)(krow + 48*D_ + 32);
        half4v af0n = *(const half4v*)(tp + 32);
        half4v af1n = *(const half4v*)(tp + 48);
        compute(ka0, kb0, af0, D2a);
        compute(ka1, kb1, af1, D2b);
        ka0 = ka0n; kb0 = kb0n; ka1 = ka1n; kb1 = kb1n; af0 = af0n; af1 = af1n;
        krow += 32*D_; tp += 32;
    }
    compute(ka0, kb0, af0, D2a);
    compute(ka1, kb1, af1, D2b);

    #pragma unroll
    for (int f = 0; f < 4; ++f) D2a[f] += D2b[f];

    {
        size_t base = ((size_t)slice * B_ + b) * 4 * N_ + (size_t)g * N_;
        const int sel = (g + 3) & 3;
        #pragma unroll
        for (int f = 0; f < 4; ++f)
            partials[base + n0 + 16*f + lm] = D2a[f][sel];
    }
}

// ---- 1-wave fallback (round-5 passing kernel) ------------------------------
template<int S>
__global__ __launch_bounds__(64, 4)
void attn2_kernel(const unsigned short* __restrict__ qb,
                  const unsigned short* __restrict__ kb,
                  const float* __restrict__ tgt,
                  float* __restrict__ partials)
{
    const int t  = threadIdx.x, lm = t & 15, g = t >> 4;
    const int b  = blockIdx.z, slice = blockIdx.y, n0 = blockIdx.x * 64;
    const int mchunk = M_ / S, mbase = slice * mchunk;

    bf16x8 qf[4][2];
    #pragma unroll
    for (int f = 0; f < 4; ++f) {
        const unsigned short* qrow = qb + ((size_t)b * N_ + n0 + 16*f + lm) * D_ + 8*g;
        qf[f][0] = *(const bf16x8*)(qrow);
        qf[f][1] = *(const bf16x8*)(qrow + 32);
    }

    const bool isones = (lm & 3) == 3;
    const int  c_ld   = isones ? 2 : (lm & 3);
    half2v one2 = pkhalf(1.0f, 1.0f);
    const half4v ones4 = __builtin_shufflevector(one2, one2, 0, 1, 0, 1);

    const unsigned short* krow = kb + ((size_t)b * M_ + mbase + lm) * D_ + 8*g;
    const float* tp = tgt + ((size_t)b * 3 + c_ld) * M_ + mbase + 4*g;

    f32x4 D2[4] = {{0,0,0,0},{0,0,0,0},{0,0,0,0},{0,0,0,0}};

    for (int ms = 0; ms < mchunk; ms += 16) {
        bf16x8 ka  = *(const bf16x8*)(krow);
        bf16x8 kb8 = *(const bf16x8*)(krow + 32);
        f32x4 tv = *(const f32x4*)(tp);
        half2v a01 = pkhalf(tv[0], tv[1]);
        half2v a23 = pkhalf(tv[2], tv[3]);
        half4v afr = __builtin_shufflevector(a01, a23, 0, 1, 2, 3);
        afr = isones ? ones4 : afr;

        #pragma unroll
        for (int f = 0; f < 4; ++f) {
            f32x4 c4 = {0,0,0,0};
            c4 = __builtin_amdgcn_mfma_f32_16x16x32_bf16(ka,  qf[f][0], c4, 0, 0, 0);
            c4 = __builtin_amdgcn_mfma_f32_16x16x32_bf16(kb8, qf[f][1], c4, 0, 0, 0);
            float e0 = EXP2(c4[0]);
            float e1 = EXP2(c4[1]);
            float e2 = EXP2(c4[2]);
            float e3 = EXP2(c4[3]);
            half2v p01 = pkhalf(e0, e1);
            half2v p23 = pkhalf(e2, e3);
            half4v pbf = __builtin_shufflevector(p01, p23, 0, 1, 2, 3);
            D2[f] = MFMA_PV(afr, pbf, D2[f]);
        }
        krow += 16 * D_;
        tp   += 16;
    }

    if (t < 16) {
        size_t base = ((size_t)slice * B_ + b) * 4 * N_;
        #pragma unroll
        for (int f = 0; f < 4; ++f) {
            int n = n0 + 16*f + t;
            partials[base + 0*N_ + n] = D2[f][3];
            partials[base + 1*N_ + n] = D2[f][0];
            partials[base + 2*N_ + n] = D2[f][1];
            partials[base + 3*N_ + n] = D2[f][2];
        }
    }
}

// ---- epilogue kernels -------------------------------------------------------
__global__ void copy_kernel(const float4* __restrict__ src, float4* __restrict__ out) {
    int i = blockIdx.x*256 + threadIdx.x;
    out[i] = src[i];
}

template<int S>
__global__ void finalize_kernel(const float* __restrict__ ws, float* __restrict__ out) {
    int tid = blockIdx.x*256 + threadIdx.x;  // B*N threads
    int b = tid >> 12;
    int n = tid & (N_-1);
    float den = 0.f, x = 0.f, y = 0.f, z = 0.f;
    #pragma unroll
    for (int s = 0; s < S; ++s) {
        size_t base = ((size_t)s*B_ + b)*4*N_ + n;
        den += ws[base];
        x   += ws[base + 1*N_];
        y   += ws[base + 2*N_];
        z   += ws[base + 3*N_];
    }
    float inv = 1.0f/den;
    out[B3N + ((size_t)b*3 + 0)*N_ + n] = x*inv;
    out[B3N + ((size_t)b*3 + 1)*N_ + n] = y*inv;
    out[B3N + ((size_t)b*3 + 2)*N_ + n] = z*inv;
}

extern "C" void kernel_launch(void* const* d_in, const int* in_sizes, int n_in,
                              void* d_out, int out_size, void* d_ws, size_t ws_size,
                              hipStream_t stream) {
    const float* qe  = (const float*)d_in[0];   // src_embedding [B,D,N]
    const float* ke  = (const float*)d_in[1];   // tgt_embedding [B,D,M]
    const float* src = (const float*)d_in[2];   // src [B,3,N]
    const float* tg  = (const float*)d_in[3];   // tgt [B,3,M]
    float* out = (float*)d_out;

    const size_t embElems = (size_t)B_ * M_ * D_;             // 2M elems (4MB bf16)
    const size_t embBytes = 2 * embElems * 2;                 // 8 MB (qb+kb)
    const size_t thBytes  = (size_t)B_ * 4 * M_ * 2;          // 256 KB
    const size_t need16   = embBytes + thBytes + (size_t)16 * B_ * 4 * N_ * 4; // ~16.25 MB
    const size_t needOld  = embBytes + (size_t)8 * B_ * 4 * N_ * 4;            // ~12.4 MB

    unsigned short* kb16 = (unsigned short*)d_ws;
    unsigned short* qb16 = kb16 + embElems;
    __fp16* th = (__fp16*)((char*)d_ws + embBytes);
    float* partialsNew = (float*)((char*)d_ws + embBytes + thBytes);
    float* partialsOld = (float*)((char*)d_ws + embBytes);

    if (ws_size >= need16) {
        prep2_kernel<<<224, 256, 0, stream>>>((const float4*)src, tg, (float4*)out, th);
        prep_kernel<<<1024, 64, 0, stream>>>(qe, ke, qb16, kb16);
        // A/B within one run: slices 0-7 via attn6 (high-TLP diet), 8-15 via attn5b (control)
        {
            dim3 gridA(N_/32, 2, B_);   // 2048 blocks x 4 waves = 32 waves/CU of work
            attn6_kernel<0><<<gridA, 256, 0, stream>>>(qb16, kb16, th, partialsNew);
        }
        {
            dim3 gridB(N_/64, 2, B_);   // 1024 blocks x 4 waves = 16 waves/CU
            attn5b_kernel<8><<<gridB, 256, 0, stream>>>(qb16, kb16, th, partialsNew);
        }
        finalize_kernel<16><<<(B_*N_)/256, 256, 0, stream>>>(partialsNew, out);
    } else if (ws_size >= needOld) {
        copy_kernel<<<96, 256, 0, stream>>>((const float4*)src, (float4*)out);
        prep_kernel<<<1024, 64, 0, stream>>>(qe, ke, qb16, kb16);
        dim3 grid(N_/64, 8, B_);
        attn2_kernel<8><<<grid, 64, 0, stream>>>(qb16, kb16, tg, partialsOld);
        finalize_kernel<8><<<(B_*N_)/256, 256, 0, stream>>>(partialsOld, out);
    }
}

// Round 11
// 44.921 us; speedup vs baseline: 5.9148x; 2.4108x over previous
//
#include <hip/hip_runtime.h>
#include <hip/hip_bf16.h>

#define B_ 8
#define D_ 64
#define N_ 4096
#define M_ 4096
#define B3N (B_*3*N_)

// exp(s/8) = exp2(s * 0.125 * log2(e)) ; SCALE2 folded into Q prepass
#define SCALE2 0.18033688011112042f

typedef short bf16x8 __attribute__((ext_vector_type(8)));
typedef float f32x4 __attribute__((ext_vector_type(4)));
typedef __fp16 half2v __attribute__((ext_vector_type(2)));
typedef __fp16 half4v __attribute__((ext_vector_type(4)));
typedef unsigned int uint4v __attribute__((ext_vector_type(4)));

#if __has_builtin(__builtin_amdgcn_exp2f)
#define EXP2(x) __builtin_amdgcn_exp2f(x)
#else
#define EXP2(x) exp2f(x)
#endif

__device__ __forceinline__ unsigned fbits(float f) { return __builtin_bit_cast(unsigned, f); }

__device__ __forceinline__ unsigned pkbf(float hi, float lo) {
#if __has_builtin(__builtin_amdgcn_perm)
    return __builtin_amdgcn_perm(fbits(hi), fbits(lo), 0x07060302u);
#else
    return (fbits(hi) & 0xFFFF0000u) | (fbits(lo) >> 16);
#endif
}

__device__ __forceinline__ half2v pkhalf(float a, float b) {
#if __has_builtin(__builtin_amdgcn_cvt_pkrtz)
    return __builtin_bit_cast(half2v, __builtin_amdgcn_cvt_pkrtz(a, b));   // low=a, high=b
#else
    half2v r; r[0] = (__fp16)a; r[1] = (__fp16)b; return r;
#endif
}

// legacy-shape MFMA builtin (V4h x V4h -> V4f), verified compiles+correct r5.
#define MFMA_PV(a,b,c) __builtin_amdgcn_mfma_f32_16x16x16f16((a),(b),(c),0,0,0)

// =============================================================================
// Swizzled layouts (fragment order):
//  emb: per (b, 16-point block): 2KB chunk, element (row lm, d=32h+8g+j) at
//       elem offset h*512 + (g*16+lm)*8 + j  -> in-kernel load = base + lane*16B
//  th:  per (b, 16-row block): 512B, lane l -> {tgt_c[m0+4*(l>>4)+r]}_{r=0..3},
//       c = l&3 (c==3 -> 1.0) -> load = base + lane*8B
// =============================================================================

// ---- prep (swizzled): [b][d][p] f32 -> fragment-order bf16, scale on Q -----
__global__ __launch_bounds__(64) void prep_swz_kernel(const float* __restrict__ qe,
                                                      const float* __restrict__ ke,
                                                      unsigned short* __restrict__ qs,
                                                      unsigned short* __restrict__ ks)
{
    int blk = blockIdx.x;            // 0..1023 ; >=512 -> Q with scale
    bool isq = blk >= 512;
    int l  = blk & 511;
    int b  = l >> 6;
    int p  = ((l & 63) << 6) + threadIdx.x;
    const float* ip = (isq ? qe : ke) + (size_t)b * D_ * M_ + p;
    unsigned short* op = (isq ? qs : ks) + (size_t)b * M_ * D_
                       + (size_t)(p >> 4) * 1024 + (p & 15) * 8;
    float sc = isq ? SCALE2 : 1.0f;
    #pragma unroll
    for (int i = 0; i < 8; ++i) {    // d = 8i..8i+7 : h=i>>2, g=i&3
        float v[8];
        #pragma unroll
        for (int d = 0; d < 8; ++d) v[d] = ip[(size_t)(8*i + d) * M_] * sc;
        uint4v w;
        #pragma unroll
        for (int j = 0; j < 4; ++j) w[j] = pkbf(v[2*j+1], v[2*j]);
        *(uint4v*)(op + (i>>2)*512 + (i&3)*128) = w;
    }
}

// ---- prep3: tgt -> fragment-order fp16 table (512B per 16-row block) -------
__global__ __launch_bounds__(64) void prep3_kernel(const float* __restrict__ tgt,
                                                   __fp16* __restrict__ thswz)
{
    int blk = blockIdx.x;            // b*256 + mblk
    int b = blk >> 8, mblk = blk & 255;
    int l = threadIdx.x;
    int c = l & 3, g = l >> 4;
    int m = mblk*16 + 4*g;
    float4 tv;
    if (c < 3) tv = *(const float4*)(tgt + ((size_t)b*3 + c)*M_ + m);
    else       tv = make_float4(1.f, 1.f, 1.f, 1.f);
    half2v a01 = pkhalf(tv.x, tv.y);
    half2v a23 = pkhalf(tv.z, tv.w);
    half4v af = __builtin_shufflevector(a01, a23, 0, 1, 2, 3);
    *(half4v*)((char*)thswz + (size_t)blk*512 + l*8) = af;
}

// ---- attn7: swizzled fragment loads, f=4, ILP-2, no LDS, no barriers -------
// All hot-loop loads are wave-contiguous: ka/kb = base+lane*16 (1KB/instr),
// af = base+lane*8 (512B/instr). Body = attn4's proven structure.
template<int S>
__global__ __launch_bounds__(256, 4)
void attn7_kernel(const unsigned short* __restrict__ qswz,
                  const unsigned short* __restrict__ kswz,
                  const __fp16* __restrict__ thswz,
                  float* __restrict__ partials)
{
    const int lane = threadIdx.x & 63;
    const int wave = threadIdx.x >> 6;
    const int lm = lane & 15, g = lane >> 4;
    const int b = blockIdx.z, slice = blockIdx.y;
    const int n0 = blockIdx.x * 256 + wave * 64;
    const int mchunk = M_ / S, mbase = slice * mchunk;

    // Q fragments: 4 blocks of 2KB starting at block n0/16
    const char* qp = (const char*)qswz
                   + ((size_t)b * N_ * D_ + (size_t)(n0 >> 4) * 1024) * 2;
    bf16x8 qf[4][2];
    #pragma unroll
    for (int f = 0; f < 4; ++f) {
        qf[f][0] = *(const bf16x8*)(qp + f*2048 + lane*16);
        qf[f][1] = *(const bf16x8*)(qp + f*2048 + 1024 + lane*16);
    }

    const char* kp = (const char*)kswz
                   + ((size_t)b * M_ * D_ + (size_t)(mbase >> 4) * 1024) * 2;
    const char* tp = (const char*)thswz
                   + ((size_t)b * (M_/16) + (size_t)(mbase >> 4)) * 512;

    f32x4 D2a[4] = {{0,0,0,0},{0,0,0,0},{0,0,0,0},{0,0,0,0}};
    f32x4 D2b[4] = {{0,0,0,0},{0,0,0,0},{0,0,0,0},{0,0,0,0}};

    auto compute = [&](bf16x8 kA, bf16x8 kB, half4v aF, f32x4* Dacc) {
        #pragma unroll
        for (int f = 0; f < 4; ++f) {
            f32x4 c4 = {0,0,0,0};
            c4 = __builtin_amdgcn_mfma_f32_16x16x32_bf16(kA, qf[f][0], c4, 0, 0, 0);
            c4 = __builtin_amdgcn_mfma_f32_16x16x32_bf16(kB, qf[f][1], c4, 0, 0, 0);
            float e0 = EXP2(c4[0]);
            float e1 = EXP2(c4[1]);
            float e2 = EXP2(c4[2]);
            float e3 = EXP2(c4[3]);
            half2v p01 = pkhalf(e0, e1);
            half2v p23 = pkhalf(e2, e3);
            half4v pbf = __builtin_shufflevector(p01, p23, 0, 1, 2, 3);
            Dacc[f] = MFMA_PV(aF, pbf, Dacc[f]);
        }
    };

    // two independent m-streams (16-row blocks 2i and 2i+1), depth-1 prefetch
    bf16x8 ka0 = *(const bf16x8*)(kp + lane*16);
    bf16x8 kb0 = *(const bf16x8*)(kp + 1024 + lane*16);
    bf16x8 ka1 = *(const bf16x8*)(kp + 2048 + lane*16);
    bf16x8 kb1 = *(const bf16x8*)(kp + 3072 + lane*16);
    half4v af0 = *(const half4v*)(tp + lane*8);
    half4v af1 = *(const half4v*)(tp + 512 + lane*8);

    const int iters = mchunk / 32;
    for (int it = 0; it < iters - 1; ++it) {
        bf16x8 ka0n = *(const bf16x8*)(kp + 4096 + lane*16);
        bf16x8 kb0n = *(const bf16x8*)(kp + 5120 + lane*16);
        bf16x8 ka1n = *(const bf16x8*)(kp + 6144 + lane*16);
        bf16x8 kb1n = *(const bf16x8*)(kp + 7168 + lane*16);
        half4v af0n = *(const half4v*)(tp + 1024 + lane*8);
        half4v af1n = *(const half4v*)(tp + 1536 + lane*8);
        compute(ka0, kb0, af0, D2a);
        compute(ka1, kb1, af1, D2b);
        ka0 = ka0n; kb0 = kb0n; ka1 = ka1n; kb1 = kb1n; af0 = af0n; af1 = af1n;
        kp += 4096; tp += 1024;
    }
    compute(ka0, kb0, af0, D2a);
    compute(ka1, kb1, af1, D2b);

    #pragma unroll
    for (int f = 0; f < 4; ++f) D2a[f] += D2b[f];

    // PV result replicated across g-groups; group g writes partials row g
    // (row0=den=D[3], row1=x=D[0], row2=y=D[1], row3=z=D[2] -> sel=(g+3)&3)
    {
        size_t base = ((size_t)slice * B_ + b) * 4 * N_ + (size_t)g * N_;
        const int sel = (g + 3) & 3;
        #pragma unroll
        for (int f = 0; f < 4; ++f)
            partials[base + n0 + 16*f + lm] = D2a[f][sel];
    }
}

// ---- old linear prep (for attn2 fallback tier only) ------------------------
__global__ __launch_bounds__(64) void prep_kernel(const float* __restrict__ qe,
                                                  const float* __restrict__ ke,
                                                  unsigned short* __restrict__ qb,
                                                  unsigned short* __restrict__ kb)
{
    int blk = blockIdx.x;
    bool isq = blk >= 512;
    int l  = blk & 511;
    int b  = l >> 6;
    int p  = ((l & 63) << 6) + threadIdx.x;
    const float* ip = (isq ? qe : ke) + (size_t)b * D_ * M_ + p;
    unsigned short* op = (isq ? qb : kb) + ((size_t)b * M_ + p) * D_;
    float sc = isq ? SCALE2 : 1.0f;
    #pragma unroll
    for (int i = 0; i < 8; ++i) {
        float v[8];
        #pragma unroll
        for (int d = 0; d < 8; ++d) v[d] = ip[(size_t)(8*i + d) * M_] * sc;
        uint4v w;
        #pragma unroll
        for (int j = 0; j < 4; ++j) w[j] = pkbf(v[2*j+1], v[2*j]);
        *(uint4v*)(op + 8*i) = w;
    }
}

// ---- 1-wave fallback (round-5 passing kernel, linear layout) ---------------
template<int S>
__global__ __launch_bounds__(64, 4)
void attn2_kernel(const unsigned short* __restrict__ qb,
                  const unsigned short* __restrict__ kb,
                  const float* __restrict__ tgt,
                  float* __restrict__ partials)
{
    const int t  = threadIdx.x, lm = t & 15, g = t >> 4;
    const int b  = blockIdx.z, slice = blockIdx.y, n0 = blockIdx.x * 64;
    const int mchunk = M_ / S, mbase = slice * mchunk;

    bf16x8 qf[4][2];
    #pragma unroll
    for (int f = 0; f < 4; ++f) {
        const unsigned short* qrow = qb + ((size_t)b * N_ + n0 + 16*f + lm) * D_ + 8*g;
        qf[f][0] = *(const bf16x8*)(qrow);
        qf[f][1] = *(const bf16x8*)(qrow + 32);
    }

    const bool isones = (lm & 3) == 3;
    const int  c_ld   = isones ? 2 : (lm & 3);
    half2v one2 = pkhalf(1.0f, 1.0f);
    const half4v ones4 = __builtin_shufflevector(one2, one2, 0, 1, 0, 1);

    const unsigned short* krow = kb + ((size_t)b * M_ + mbase + lm) * D_ + 8*g;
    const float* tp = tgt + ((size_t)b * 3 + c_ld) * M_ + mbase + 4*g;

    f32x4 D2[4] = {{0,0,0,0},{0,0,0,0},{0,0,0,0},{0,0,0,0}};

    for (int ms = 0; ms < mchunk; ms += 16) {
        bf16x8 ka  = *(const bf16x8*)(krow);
        bf16x8 kb8 = *(const bf16x8*)(krow + 32);
        f32x4 tv = *(const f32x4*)(tp);
        half2v a01 = pkhalf(tv[0], tv[1]);
        half2v a23 = pkhalf(tv[2], tv[3]);
        half4v afr = __builtin_shufflevector(a01, a23, 0, 1, 2, 3);
        afr = isones ? ones4 : afr;

        #pragma unroll
        for (int f = 0; f < 4; ++f) {
            f32x4 c4 = {0,0,0,0};
            c4 = __builtin_amdgcn_mfma_f32_16x16x32_bf16(ka,  qf[f][0], c4, 0, 0, 0);
            c4 = __builtin_amdgcn_mfma_f32_16x16x32_bf16(kb8, qf[f][1], c4, 0, 0, 0);
            float e0 = EXP2(c4[0]);
            float e1 = EXP2(c4[1]);
            float e2 = EXP2(c4[2]);
            float e3 = EXP2(c4[3]);
            half2v p01 = pkhalf(e0, e1);
            half2v p23 = pkhalf(e2, e3);
            half4v pbf = __builtin_shufflevector(p01, p23, 0, 1, 2, 3);
            D2[f] = MFMA_PV(afr, pbf, D2[f]);
        }
        krow += 16 * D_;
        tp   += 16;
    }

    if (t < 16) {
        size_t base = ((size_t)slice * B_ + b) * 4 * N_;
        #pragma unroll
        for (int f = 0; f < 4; ++f) {
            int n = n0 + 16*f + t;
            partials[base + 0*N_ + n] = D2[f][3];
            partials[base + 1*N_ + n] = D2[f][0];
            partials[base + 2*N_ + n] = D2[f][1];
            partials[base + 3*N_ + n] = D2[f][2];
        }
    }
}

// ---- epilogue kernels -------------------------------------------------------
__global__ void copy_kernel(const float4* __restrict__ src, float4* __restrict__ out) {
    int i = blockIdx.x*256 + threadIdx.x;   // grid = 96
    out[i] = src[i];
}

template<int S>
__global__ void finalize_kernel(const float* __restrict__ ws, float* __restrict__ out) {
    int tid = blockIdx.x*256 + threadIdx.x;  // B*N threads
    int b = tid >> 12;
    int n = tid & (N_-1);
    float den = 0.f, x = 0.f, y = 0.f, z = 0.f;
    #pragma unroll
    for (int s = 0; s < S; ++s) {
        size_t base = ((size_t)s*B_ + b)*4*N_ + n;
        den += ws[base];
        x   += ws[base + 1*N_];
        y   += ws[base + 2*N_];
        z   += ws[base + 3*N_];
    }
    float inv = 1.0f/den;
    out[B3N + ((size_t)b*3 + 0)*N_ + n] = x*inv;
    out[B3N + ((size_t)b*3 + 1)*N_ + n] = y*inv;
    out[B3N + ((size_t)b*3 + 2)*N_ + n] = z*inv;
}

extern "C" void kernel_launch(void* const* d_in, const int* in_sizes, int n_in,
                              void* d_out, int out_size, void* d_ws, size_t ws_size,
                              hipStream_t stream) {
    const float* qe  = (const float*)d_in[0];   // src_embedding [B,D,N]
    const float* ke  = (const float*)d_in[1];   // tgt_embedding [B,D,M]
    const float* src = (const float*)d_in[2];   // src [B,3,N]
    const float* tg  = (const float*)d_in[3];   // tgt [B,3,M]
    float* out = (float*)d_out;

    const size_t embElems = (size_t)B_ * M_ * D_;             // 2M elems (4MB bf16)
    const size_t embBytes = 2 * embElems * 2;                 // 8 MB (q+k)
    const size_t thBytes  = (size_t)B_ * 256 * 512;           // 1 MB swizzled th
    const size_t partB8   = (size_t)8 * B_ * 4 * N_ * 4;      // 4 MB
    const size_t needSwz  = embBytes + thBytes + partB8;      // ~13 MB
    const size_t needOld  = embBytes + partB8;                // ~12 MB

    unsigned short* kb16 = (unsigned short*)d_ws;
    unsigned short* qb16 = kb16 + embElems;
    __fp16* thswz = (__fp16*)((char*)d_ws + embBytes);
    float* partialsNew = (float*)((char*)d_ws + embBytes + thBytes);
    float* partialsOld = (float*)((char*)d_ws + embBytes);

    if (ws_size >= needSwz) {
        copy_kernel<<<96, 256, 0, stream>>>((const float4*)src, (float4*)out);
        prep_swz_kernel<<<1024, 64, 0, stream>>>(qe, ke, qb16, kb16);
        prep3_kernel<<<B_*256, 64, 0, stream>>>(tg, thswz);
        dim3 grid(N_/256, 8, B_);   // 1024 blocks x 4 waves = 16 waves/CU
        attn7_kernel<8><<<grid, 256, 0, stream>>>(qb16, kb16, thswz, partialsNew);
        finalize_kernel<8><<<(B_*N_)/256, 256, 0, stream>>>(partialsNew, out);
    } else if (ws_size >= needOld) {
        copy_kernel<<<96, 256, 0, stream>>>((const float4*)src, (float4*)out);
        prep_kernel<<<1024, 64, 0, stream>>>(qe, ke, qb16, kb16);
        dim3 grid(N_/64, 8, B_);
        attn2_kernel<8><<<grid, 64, 0, stream>>>(qb16, kb16, tg, partialsOld);
        finalize_kernel<8><<<(B_*N_)/256, 256, 0, stream>>>(partialsOld, out);
    }
}

// Round 12
// 37.692 us; speedup vs baseline: 7.0492x; 1.1918x over previous
//
#include <hip/hip_runtime.h>
#include <hip/hip_bf16.h>

#define B_ 8
#define D_ 64
#define N_ 4096
#define M_ 4096
#define B3N (B_*3*N_)

// exp(s/8) = exp2(s * 0.125 * log2(e)) ; SCALE2 folded into Q prepass
#define SCALE2 0.18033688011112042f

typedef short bf16x8 __attribute__((ext_vector_type(8)));
typedef float f32x4 __attribute__((ext_vector_type(4)));
typedef __fp16 half2v __attribute__((ext_vector_type(2)));
typedef __fp16 half4v __attribute__((ext_vector_type(4)));
typedef unsigned int uint4v __attribute__((ext_vector_type(4)));

#if __has_builtin(__builtin_amdgcn_exp2f)
#define EXP2(x) __builtin_amdgcn_exp2f(x)
#else
#define EXP2(x) exp2f(x)
#endif

__device__ __forceinline__ unsigned fbits(float f) { return __builtin_bit_cast(unsigned, f); }

__device__ __forceinline__ unsigned pkbf(float hi, float lo) {
#if __has_builtin(__builtin_amdgcn_perm)
    return __builtin_amdgcn_perm(fbits(hi), fbits(lo), 0x07060302u);
#else
    return (fbits(hi) & 0xFFFF0000u) | (fbits(lo) >> 16);
#endif
}

__device__ __forceinline__ half2v pkhalf(float a, float b) {
#if __has_builtin(__builtin_amdgcn_cvt_pkrtz)
    return __builtin_bit_cast(half2v, __builtin_amdgcn_cvt_pkrtz(a, b));   // low=a, high=b
#else
    half2v r; r[0] = (__fp16)a; r[1] = (__fp16)b; return r;
#endif
}

// legacy-shape MFMA builtin (V4h x V4h -> V4f), verified compiles+correct r5.
#define MFMA_PV(a,b,c) __builtin_amdgcn_mfma_f32_16x16x16f16((a),(b),(c),0,0,0)

// =============================================================================
// Swizzled layouts (fragment order):
//  emb: per (b, 16-point block): 2KB chunk, element (row lm, d=32h+8g+j) at
//       elem offset h*512 + (g*16+lm)*8 + j  -> load = base + lane*16B
//  th:  per (b, 16-row block): 512B, lane l -> {tgt_c[m0+4*(l>>4)+r]}_{r=0..3},
//       c = l&3 (c==3 -> 1.0) -> load = base + lane*8B
// =============================================================================

// ---- prep (swizzled): [b][d][p] f32 -> fragment-order bf16, scale on Q -----
__global__ __launch_bounds__(64) void prep_swz_kernel(const float* __restrict__ qe,
                                                      const float* __restrict__ ke,
                                                      unsigned short* __restrict__ qs,
                                                      unsigned short* __restrict__ ks)
{
    int blk = blockIdx.x;            // 0..1023 ; >=512 -> Q with scale
    bool isq = blk >= 512;
    int l  = blk & 511;
    int b  = l >> 6;
    int p  = ((l & 63) << 6) + threadIdx.x;
    const float* ip = (isq ? qe : ke) + (size_t)b * D_ * M_ + p;
    unsigned short* op = (isq ? qs : ks) + (size_t)b * M_ * D_
                       + (size_t)(p >> 4) * 1024 + (p & 15) * 8;
    float sc = isq ? SCALE2 : 1.0f;
    #pragma unroll
    for (int i = 0; i < 8; ++i) {    // d = 8i..8i+7 : h=i>>2, g=i&3
        float v[8];
        #pragma unroll
        for (int d = 0; d < 8; ++d) v[d] = ip[(size_t)(8*i + d) * M_] * sc;
        uint4v w;
        #pragma unroll
        for (int j = 0; j < 4; ++j) w[j] = pkbf(v[2*j+1], v[2*j]);
        *(uint4v*)(op + (i>>2)*512 + (i&3)*128) = w;
    }
}

// ---- prep3: src copy-through + tgt -> fragment-order fp16 table ------------
__global__ __launch_bounds__(256) void prep3_kernel(const float4* __restrict__ src4,
                                                    const float* __restrict__ tgt,
                                                    float4* __restrict__ out4,
                                                    __fp16* __restrict__ thswz)
{
    int blk = blockIdx.x;
    if (blk < 96) {                           // 96*256 = B*3*N/4 float4s
        int i = blk*256 + threadIdx.x;
        out4[i] = src4[i];
        return;
    }
    int unit = (blk - 96)*4 + (threadIdx.x >> 6);   // 0..2047 = b*256+mblk
    int b = unit >> 8, mblk = unit & 255;
    int l = threadIdx.x & 63;
    int c = l & 3, g = l >> 4;
    int m = mblk*16 + 4*g;
    float4 tv;
    if (c < 3) tv = *(const float4*)(tgt + ((size_t)b*3 + c)*M_ + m);
    else       tv = make_float4(1.f, 1.f, 1.f, 1.f);
    half2v a01 = pkhalf(tv.x, tv.y);
    half2v a23 = pkhalf(tv.z, tv.w);
    half4v af = __builtin_shufflevector(a01, a23, 0, 1, 2, 3);
    *(half4v*)((char*)thswz + (size_t)unit*512 + l*8) = af;
}

// ---- attn8: LDS-staged K/af (4 waves share one K stream), double-buffered --
// 4 waves/block: same (b, slice, m-range), different n0 -> K read ONCE per
// block (was 4x). Wave w stages K-chunk w (1KB, reg->ds_write); wave 0 stages
// the 1KB af pair. One barrier/iter. All ds_reads canonical lane*16 / lane*8.
template<int S>
__global__ __launch_bounds__(256, 4)
void attn8_kernel(const unsigned short* __restrict__ qswz,
                  const unsigned short* __restrict__ kswz,
                  const __fp16* __restrict__ thswz,
                  float* __restrict__ partials)
{
    __shared__ __align__(16) unsigned char kbuf[2][4096];
    __shared__ __align__(16) unsigned char abuf[2][1024];

    const int lane = threadIdx.x & 63;
    const int wave = threadIdx.x >> 6;
    const int lm = lane & 15, g = lane >> 4;
    const int b = blockIdx.z, slice = blockIdx.y;
    const int n0 = blockIdx.x * 256 + wave * 64;
    const int mchunk = M_ / S, mbase = slice * mchunk;

    // Q fragments (per-wave, VMEM once): 4 blocks of 2KB from block n0/16
    const char* qp = (const char*)qswz
                   + ((size_t)b * N_ * D_ + (size_t)(n0 >> 4) * 1024) * 2;
    bf16x8 qf[4][2];
    #pragma unroll
    for (int f = 0; f < 4; ++f) {
        qf[f][0] = *(const bf16x8*)(qp + f*2048 + lane*16);
        qf[f][1] = *(const bf16x8*)(qp + f*2048 + 1024 + lane*16);
    }

    const char* kp = (const char*)kswz
                   + ((size_t)b * M_ * D_ + (size_t)(mbase >> 4) * 1024) * 2;
    const char* tp = (const char*)thswz
                   + ((size_t)b * (M_/16) + (size_t)(mbase >> 4)) * 512;

    // prologue: stage iteration 0
    {
        bf16x8 k0 = *(const bf16x8*)(kp + wave*1024 + lane*16);
        *(bf16x8*)(kbuf[0] + wave*1024 + lane*16) = k0;
        if (wave == 0) {
            uint4v a0 = *(const uint4v*)(tp + lane*16);
            *(uint4v*)(abuf[0] + lane*16) = a0;
        }
    }
    __syncthreads();

    f32x4 D2[4] = {{0,0,0,0},{0,0,0,0},{0,0,0,0},{0,0,0,0}};

    auto compute = [&](bf16x8 kA, bf16x8 kB, half4v aF) {
        #pragma unroll
        for (int f = 0; f < 4; ++f) {
            f32x4 c4 = {0,0,0,0};
            c4 = __builtin_amdgcn_mfma_f32_16x16x32_bf16(kA, qf[f][0], c4, 0, 0, 0);
            c4 = __builtin_amdgcn_mfma_f32_16x16x32_bf16(kB, qf[f][1], c4, 0, 0, 0);
            float e0 = EXP2(c4[0]);
            float e1 = EXP2(c4[1]);
            float e2 = EXP2(c4[2]);
            float e3 = EXP2(c4[3]);
            half2v p01 = pkhalf(e0, e1);
            half2v p23 = pkhalf(e2, e3);
            half4v pbf = __builtin_shufflevector(p01, p23, 0, 1, 2, 3);
            D2[f] = MFMA_PV(aF, pbf, D2[f]);
        }
    };

    int cur = 0;
    const int iters = mchunk / 32;   // 16: 32 m-rows per iteration
    for (int it = 0; it < iters; ++it) {
        bf16x8 knxt;
        uint4v anxt;
        const bool more = (it < iters - 1);
        if (more) {
            knxt = *(const bf16x8*)(kp + 4096 + wave*1024 + lane*16);
            if (wave == 0) anxt = *(const uint4v*)(tp + 1024 + lane*16);
        }
        // ds reads (conflict-free): 4x b128 + 2x b64
        bf16x8 ka0 = *(const bf16x8*)(kbuf[cur] + 0*1024 + lane*16);
        bf16x8 kb0 = *(const bf16x8*)(kbuf[cur] + 1*1024 + lane*16);
        bf16x8 ka1 = *(const bf16x8*)(kbuf[cur] + 2*1024 + lane*16);
        bf16x8 kb1 = *(const bf16x8*)(kbuf[cur] + 3*1024 + lane*16);
        half4v af0 = *(const half4v*)(abuf[cur] + lane*8);
        half4v af1 = *(const half4v*)(abuf[cur] + 512 + lane*8);

        compute(ka0, kb0, af0);
        compute(ka1, kb1, af1);

        if (more) {
            *(bf16x8*)(kbuf[cur^1] + wave*1024 + lane*16) = knxt;
            if (wave == 0) *(uint4v*)(abuf[cur^1] + lane*16) = anxt;
            kp += 4096; tp += 1024;
        }
        __syncthreads();
        cur ^= 1;
    }

    // PV result replicated across g-groups; group g writes partials row g
    // (row0=den=D[3], row1=x=D[0], row2=y=D[1], row3=z=D[2] -> sel=(g+3)&3)
    {
        size_t base = ((size_t)slice * B_ + b) * 4 * N_ + (size_t)g * N_;
        const int sel = (g + 3) & 3;
        #pragma unroll
        for (int f = 0; f < 4; ++f)
            partials[base + n0 + 16*f + lm] = D2[f][sel];
    }
}

// ---- old linear prep (for attn2 fallback tier only) ------------------------
__global__ __launch_bounds__(64) void prep_kernel(const float* __restrict__ qe,
                                                  const float* __restrict__ ke,
                                                  unsigned short* __restrict__ qb,
                                                  unsigned short* __restrict__ kb)
{
    int blk = blockIdx.x;
    bool isq = blk >= 512;
    int l  = blk & 511;
    int b  = l >> 6;
    int p  = ((l & 63) << 6) + threadIdx.x;
    const float* ip = (isq ? qe : ke) + (size_t)b * D_ * M_ + p;
    unsigned short* op = (isq ? qb : kb) + ((size_t)b * M_ + p) * D_;
    float sc = isq ? SCALE2 : 1.0f;
    #pragma unroll
    for (int i = 0; i < 8; ++i) {
        float v[8];
        #pragma unroll
        for (int d = 0; d < 8; ++d) v[d] = ip[(size_t)(8*i + d) * M_] * sc;
        uint4v w;
        #pragma unroll
        for (int j = 0; j < 4; ++j) w[j] = pkbf(v[2*j+1], v[2*j]);
        *(uint4v*)(op + 8*i) = w;
    }
}

// ---- 1-wave fallback (round-5 passing kernel, linear layout) ---------------
template<int S>
__global__ __launch_bounds__(64, 4)
void attn2_kernel(const unsigned short* __restrict__ qb,
                  const unsigned short* __restrict__ kb,
                  const float* __restrict__ tgt,
                  float* __restrict__ partials)
{
    const int t  = threadIdx.x, lm = t & 15, g = t >> 4;
    const int b  = blockIdx.z, slice = blockIdx.y, n0 = blockIdx.x * 64;
    const int mchunk = M_ / S, mbase = slice * mchunk;

    bf16x8 qf[4][2];
    #pragma unroll
    for (int f = 0; f < 4; ++f) {
        const unsigned short* qrow = qb + ((size_t)b * N_ + n0 + 16*f + lm) * D_ + 8*g;
        qf[f][0] = *(const bf16x8*)(qrow);
        qf[f][1] = *(const bf16x8*)(qrow + 32);
    }

    const bool isones = (lm & 3) == 3;
    const int  c_ld   = isones ? 2 : (lm & 3);
    half2v one2 = pkhalf(1.0f, 1.0f);
    const half4v ones4 = __builtin_shufflevector(one2, one2, 0, 1, 0, 1);

    const unsigned short* krow = kb + ((size_t)b * M_ + mbase + lm) * D_ + 8*g;
    const float* tp = tgt + ((size_t)b * 3 + c_ld) * M_ + mbase + 4*g;

    f32x4 D2[4] = {{0,0,0,0},{0,0,0,0},{0,0,0,0},{0,0,0,0}};

    for (int ms = 0; ms < mchunk; ms += 16) {
        bf16x8 ka  = *(const bf16x8*)(krow);
        bf16x8 kb8 = *(const bf16x8*)(krow + 32);
        f32x4 tv = *(const f32x4*)(tp);
        half2v a01 = pkhalf(tv[0], tv[1]);
        half2v a23 = pkhalf(tv[2], tv[3]);
        half4v afr = __builtin_shufflevector(a01, a23, 0, 1, 2, 3);
        afr = isones ? ones4 : afr;

        #pragma unroll
        for (int f = 0; f < 4; ++f) {
            f32x4 c4 = {0,0,0,0};
            c4 = __builtin_amdgcn_mfma_f32_16x16x32_bf16(ka,  qf[f][0], c4, 0, 0, 0);
            c4 = __builtin_amdgcn_mfma_f32_16x16x32_bf16(kb8, qf[f][1], c4, 0, 0, 0);
            float e0 = EXP2(c4[0]);
            float e1 = EXP2(c4[1]);
            float e2 = EXP2(c4[2]);
            float e3 = EXP2(c4[3]);
            half2v p01 = pkhalf(e0, e1);
            half2v p23 = pkhalf(e2, e3);
            half4v pbf = __builtin_shufflevector(p01, p23, 0, 1, 2, 3);
            D2[f] = MFMA_PV(afr, pbf, D2[f]);
        }
        krow += 16 * D_;
        tp   += 16;
    }

    if (t < 16) {
        size_t base = ((size_t)slice * B_ + b) * 4 * N_;
        #pragma unroll
        for (int f = 0; f < 4; ++f) {
            int n = n0 + 16*f + t;
            partials[base + 0*N_ + n] = D2[f][3];
            partials[base + 1*N_ + n] = D2[f][0];
            partials[base + 2*N_ + n] = D2[f][1];
            partials[base + 3*N_ + n] = D2[f][2];
        }
    }
}

// ---- epilogue kernels -------------------------------------------------------
__global__ void copy_kernel(const float4* __restrict__ src, float4* __restrict__ out) {
    int i = blockIdx.x*256 + threadIdx.x;   // grid = 96
    out[i] = src[i];
}

template<int S>
__global__ void finalize_kernel(const float* __restrict__ ws, float* __restrict__ out) {
    int tid = blockIdx.x*256 + threadIdx.x;  // B*N threads
    int b = tid >> 12;
    int n = tid & (N_-1);
    float den = 0.f, x = 0.f, y = 0.f, z = 0.f;
    #pragma unroll
    for (int s = 0; s < S; ++s) {
        size_t base = ((size_t)s*B_ + b)*4*N_ + n;
        den += ws[base];
        x   += ws[base + 1*N_];
        y   += ws[base + 2*N_];
        z   += ws[base + 3*N_];
    }
    float inv = 1.0f/den;
    out[B3N + ((size_t)b*3 + 0)*N_ + n] = x*inv;
    out[B3N + ((size_t)b*3 + 1)*N_ + n] = y*inv;
    out[B3N + ((size_t)b*3 + 2)*N_ + n] = z*inv;
}

extern "C" void kernel_launch(void* const* d_in, const int* in_sizes, int n_in,
                              void* d_out, int out_size, void* d_ws, size_t ws_size,
                              hipStream_t stream) {
    const float* qe  = (const float*)d_in[0];   // src_embedding [B,D,N]
    const float* ke  = (const float*)d_in[1];   // tgt_embedding [B,D,M]
    const float* src = (const float*)d_in[2];   // src [B,3,N]
    const float* tg  = (const float*)d_in[3];   // tgt [B,3,M]
    float* out = (float*)d_out;

    const size_t embElems = (size_t)B_ * M_ * D_;             // 2M elems (4MB bf16)
    const size_t embBytes = 2 * embElems * 2;                 // 8 MB (q+k)
    const size_t thBytes  = (size_t)B_ * 256 * 512;           // 1 MB swizzled th
    const size_t partB8   = (size_t)8 * B_ * 4 * N_ * 4;      // 4 MB
    const size_t needSwz  = embBytes + thBytes + partB8;      // ~13 MB
    const size_t needOld  = embBytes + partB8;                // ~12 MB

    unsigned short* kb16 = (unsigned short*)d_ws;
    unsigned short* qb16 = kb16 + embElems;
    __fp16* thswz = (__fp16*)((char*)d_ws + embBytes);
    float* partialsNew = (float*)((char*)d_ws + embBytes + thBytes);
    float* partialsOld = (float*)((char*)d_ws + embBytes);

    if (ws_size >= needSwz) {
        prep_swz_kernel<<<1024, 64, 0, stream>>>(qe, ke, qb16, kb16);
        prep3_kernel<<<608, 256, 0, stream>>>((const float4*)src, tg, (float4*)out, thswz);
        dim3 grid(N_/256, 8, B_);   // 1024 blocks x 4 waves = 16 waves/CU (1 full round)
        attn8_kernel<8><<<grid, 256, 0, stream>>>(qb16, kb16, thswz, partialsNew);
        finalize_kernel<8><<<(B_*N_)/256, 256, 0, stream>>>(partialsNew, out);
    } else if (ws_size >= needOld) {
        copy_kernel<<<96, 256, 0, stream>>>((const float4*)src, (float4*)out);
        prep_kernel<<<1024, 64, 0, stream>>>(qe, ke, qb16, kb16);
        dim3 grid(N_/64, 8, B_);
        attn2_kernel<8><<<grid, 64, 0, stream>>>(qb16, kb16, tg, partialsOld);
        finalize_kernel<8><<<(B_*N_)/256, 256, 0, stream>>>(partialsOld, out);
    }
}